// Round 4
// baseline (880.055 us; speedup 1.0000x reference)
//
#include <hip/hip_runtime.h>
#include <hip/hip_bf16.h>

// ChildSumTreeLSTM, fp32 in/out, depth=17, N=2^18-1, D_IN=H=128.
// R4 structure:
//  k_prep : swizzle weights. W (4): plain bf16 (x-path error is per-node random).
//           U (4): split-2 hi/lo bf16 (h-path error would be coherent).
//  k_main : one streaming GEMM over ALL nodes: internal rows -> X=x@W+b (bf16,
//           4 planes); leaf rows -> fused epilogue writes h (bf16), c_leaf (bf16).
//  k_level: U-GEMMs only. Wave owns cols [32w,32w+32) of ALL gates -> i/o/u/f
//           for a column in one wave; in-lane f*c child-pair reduction; one
//           LDS exchange; 3 barriers total; X/c read directly in epilogue.
//  k_out  : root (h, c) -> 256 fp32.

typedef __bf16 bf16_t;
typedef __bf16 bf16x8 __attribute__((ext_vector_type(8)));
typedef float  f32x4  __attribute__((ext_vector_type(4)));

#define MFMA16(a, b, c) __builtin_amdgcn_mfma_f32_16x16x32_bf16((a), (b), (c), 0, 0, 0)

__device__ __forceinline__ float sigm(float x) { return 1.0f / (1.0f + __expf(-x)); }
__device__ __forceinline__ float tanh_(float x) {
    float a = fabsf(x);
    float e = __expf(2.0f * a);
    float t = 1.0f - 2.0f / (e + 1.0f);
    return copysignf(t, x);
}

__device__ __forceinline__ void cvt16(const float* __restrict__ src, bf16_t* __restrict__ dst)
{
    float tmp[16];
    *(float4*)&tmp[0]  = ((const float4*)src)[0];
    *(float4*)&tmp[4]  = ((const float4*)src)[1];
    *(float4*)&tmp[8]  = ((const float4*)src)[2];
    *(float4*)&tmp[12] = ((const float4*)src)[3];
    bf16_t b[16];
#pragma unroll
    for (int j = 0; j < 16; j++) b[j] = (bf16_t)tmp[j];
    *(bf16x8*)&dst[0] = *(bf16x8*)&b[0];
    *(bf16x8*)&dst[8] = *(bf16x8*)&b[8];
}

__device__ __forceinline__ void zero16(bf16_t* __restrict__ dst)
{
    bf16x8 z = (bf16x8)(bf16_t)0.f;
    *(bf16x8*)&dst[0] = z;
    *(bf16x8*)&dst[8] = z;
}

// ---------------------------------------------------------------------------
// SW layout: W slot g (g=0..3: Wi,Wf,Wo,Wu) at SW + g*16384 (hi only).
//            U slot u (u=0..3: Ui,Uf,Uo,Uu) at SW + 65536 + u*32768 (hi), +16384 (lo).
// idx = ((nt*4+kb)*64+lane)*8 + j ; element = M[kb*32+(lane>>4)*8+j][nt*16+(lane&15)]
__global__ __launch_bounds__(256)
void k_prep(const float* __restrict__ Wi, const float* __restrict__ Wf,
            const float* __restrict__ Wo, const float* __restrict__ Wu,
            const float* __restrict__ Ui, const float* __restrict__ Uf,
            const float* __restrict__ Uo, const float* __restrict__ Uu,
            bf16_t* __restrict__ SW)
{
    int b = blockIdx.x;
    const float* src;
    switch (b) {
        case 0: src = Wi; break; case 1: src = Wf; break;
        case 2: src = Wo; break; case 3: src = Wu; break;
        case 4: src = Ui; break; case 5: src = Uf; break;
        case 6: src = Uo; break; default: src = Uu; break;
    }
    if (b < 4) {
        bf16_t* hi = SW + (size_t)b * 16384;
        for (int idx = threadIdx.x; idx < 16384; idx += 256) {
            int j = idx & 7, lane = (idx >> 3) & 63, kb = (idx >> 9) & 3, nt = idx >> 11;
            int k = kb * 32 + (lane >> 4) * 8 + j;
            int n = nt * 16 + (lane & 15);
            hi[idx] = (bf16_t)src[k * 128 + n];
        }
    } else {
        bf16_t* hi = SW + 65536 + (size_t)(b - 4) * 32768;
        bf16_t* lo = hi + 16384;
        for (int idx = threadIdx.x; idx < 16384; idx += 256) {
            int j = idx & 7, lane = (idx >> 3) & 63, kb = (idx >> 9) & 3, nt = idx >> 11;
            int k = kb * 32 + (lane >> 4) * 8 + j;
            int n = nt * 16 + (lane & 15);
            float w = src[k * 128 + n];
            bf16_t hh = (bf16_t)w;
            hi[idx] = hh;
            lo[idx] = (bf16_t)(w - (float)hh);
        }
    }
}

// ---------------------------------------------------------------------------
// k_main: 64 rows/block. bid < iB: internal rows -> X planes. else: leaf rows
// -> fused leaf epilogue. Wave = gate (internal) or 96-col strip of [i|o|u] (leaf).
__global__ __launch_bounds__(256)
void k_main(const float* __restrict__ x, const bf16_t* __restrict__ SW,
            const float* __restrict__ bi, const float* __restrict__ bf_,
            const float* __restrict__ bo, const float* __restrict__ bu,
            bf16_t* __restrict__ X, bf16_t* __restrict__ h,
            bf16_t* __restrict__ cLeaf,
            int Mint, int Ntot, int iB)
{
    __shared__ __align__(16) char smem[25616];
    bf16_t (*A)[136]  = (bf16_t(*)[136])(smem);   // 17408 B staging
    float  (*Ch)[100] = (float(*)[100])(smem);    // 25600 B leaf dump (aliased)

    const int tid  = threadIdx.x;
    const bool leafBlk = (blockIdx.x >= iB);
    const int row0 = leafBlk ? (Mint + 64 * (blockIdx.x - iB)) : (64 * blockIdx.x);
    const int rowLim = leafBlk ? Ntot : Mint;

    // stage A: 64 rows x 128 cols fp32 -> bf16
#pragma unroll
    for (int it = 0; it < 2; it++) {
        int chunk = tid + it * 256;
        int r = chunk >> 3, cb = (chunk & 7) * 16;
        if (row0 + r < rowLim) cvt16(x + (size_t)(row0 + r) * 128 + cb, &A[r][cb]);
        else                   zero16(&A[r][cb]);
    }
    __syncthreads();

    const int wave = tid >> 6, lane = tid & 63;
    const int quad = lane >> 4, lc = lane & 15;

    f32x4 acc[8][4];
#pragma unroll
    for (int nt = 0; nt < 8; nt++)
#pragma unroll
        for (int mt = 0; mt < 4; mt++) acc[nt][mt] = (f32x4){0.f, 0.f, 0.f, 0.f};

    if (!leafBlk) {
        const bf16_t* Wg = SW + (size_t)wave * 16384;
        for (int kb = 0; kb < 4; kb++) {
            const int k0 = kb * 32 + quad * 8;
            bf16x8 a[4];
#pragma unroll
            for (int mt = 0; mt < 4; mt++) a[mt] = *(const bf16x8*)&A[mt * 16 + lc][k0];
#pragma unroll
            for (int nt = 0; nt < 8; nt++) {
                bf16x8 bw = *(const bf16x8*)(Wg + ((size_t)(nt * 4 + kb) * 64 + lane) * 8);
#pragma unroll
                for (int mt = 0; mt < 4; mt++) acc[nt][mt] = MFMA16(a[mt], bw, acc[nt][mt]);
            }
        }
        // epilogue: X[g][row][col] = acc + bias (bf16)
        const float* bg = (wave == 0) ? bi : (wave == 1) ? bf_ : (wave == 2) ? bo : bu;
        bf16_t* Xg = X + (size_t)wave * Mint * 128;
#pragma unroll
        for (int nt = 0; nt < 8; nt++) {
            int colg = nt * 16 + lc;
            float bias = bg[colg];
#pragma unroll
            for (int mt = 0; mt < 4; mt++)
#pragma unroll
                for (int r = 0; r < 4; r++) {
                    int row = row0 + mt * 16 + quad * 4 + r;
                    if (row < Mint) Xg[(size_t)row * 128 + colg] = (bf16_t)(acc[nt][mt][r] + bias);
                }
        }
    } else {
        // leaf: 6 col-tiles per wave over [i|o|u] concat (384 cols)
        for (int kb = 0; kb < 4; kb++) {
            const int k0 = kb * 32 + quad * 8;
            bf16x8 a[4];
#pragma unroll
            for (int mt = 0; mt < 4; mt++) a[mt] = *(const bf16x8*)&A[mt * 16 + lc][k0];
#pragma unroll
            for (int nt = 0; nt < 6; nt++) {
                int colb = wave * 96 + nt * 16;
                int g = colb >> 7;                           // 0=i,1=o,2=u
                int slot = (g == 0) ? 0 : (g == 1) ? 2 : 3;  // Wi,Wo,Wu
                int ntg = (colb & 127) >> 4;
                bf16x8 bw = *(const bf16x8*)(SW + (size_t)slot * 16384 +
                                             ((size_t)(ntg * 4 + kb) * 64 + lane) * 8);
#pragma unroll
                for (int mt = 0; mt < 4; mt++) acc[nt][mt] = MFMA16(a[mt], bw, acc[nt][mt]);
            }
        }
        // 4-phase epilogue over 32-col quarters of each gate
        for (int p = 0; p < 4; p++) {
            __syncthreads();
#pragma unroll
            for (int nt = 0; nt < 6; nt++) {
                int colb = wave * 96 + nt * 16;
                int g = colb >> 7;
                int cq = (colb & 127) >> 5;
                if (cq == p) {
                    int dst = g * 32 + (colb & 31);
#pragma unroll
                    for (int mt = 0; mt < 4; mt++)
#pragma unroll
                        for (int r = 0; r < 4; r++)
                            Ch[mt * 16 + quad * 4 + r][dst + lc] = acc[nt][mt][r];
                }
            }
            __syncthreads();
            for (int idx = tid; idx < 64 * 32; idx += 256) {
                int m = idx >> 5, jj = idx & 31, j = p * 32 + jj;
                int node = row0 + m;
                if (node < Ntot) {
                    float iv = sigm(Ch[m][jj] + bi[j]);
                    float ov = sigm(Ch[m][32 + jj] + bo[j]);
                    float uv = tanh_(Ch[m][64 + jj] + bu[j]);
                    float cv = iv * uv;
                    float hv = ov * tanh_(cv);
                    h[(size_t)node * 128 + j] = (bf16_t)hv;
                    cLeaf[(size_t)(node - Mint) * 128 + j] = (bf16_t)cv;
                }
            }
        }
    }
}

// ---------------------------------------------------------------------------
// k_level: 32 parents/block. Wave w owns cols [32w,32w+32) of i,o,u (on ht)
// and f (on hc, 64 child rows). Split-2 U weights.
__global__ __launch_bounds__(256)
void k_level(const bf16_t* __restrict__ X, const bf16_t* __restrict__ SW,
             bf16_t* __restrict__ h, float* __restrict__ cInt,
             const bf16_t* __restrict__ cLeaf,
             int Mint, int sl, int nl)
{
    __shared__ __align__(16) bf16_t HC[64][136];   // children h
    __shared__ __align__(16) bf16_t HT[32][136];   // child-sum
    __shared__ __align__(16) float  S[32][132];    // f0*c0+f1*c1 exchange

    const int tid = threadIdx.x;
    const int n0  = blockIdx.x * 32;
    const int sl2 = 2 * sl + 1;                    // child level start
    const int nch = 2 * nl;                        // children in child level

    {   // stage 64 children h rows (bf16 raw copy), zero beyond level
        int r = tid >> 2, cb = (tid & 3) * 32;
        int row = 2 * n0 + r;
        if (row < nch) {
            const uint4* src = (const uint4*)(h + (size_t)(sl2 + row) * 128 + cb);
            *(uint4*)&HC[r][cb]      = src[0];
            *(uint4*)&HC[r][cb + 8]  = src[1];
            *(uint4*)&HC[r][cb + 16] = src[2];
            *(uint4*)&HC[r][cb + 24] = src[3];
        } else {
            uint4 z = {0u, 0u, 0u, 0u};
            *(uint4*)&HC[r][cb]      = z;
            *(uint4*)&HC[r][cb + 8]  = z;
            *(uint4*)&HC[r][cb + 16] = z;
            *(uint4*)&HC[r][cb + 24] = z;
        }
    }
    __syncthreads();
    for (int ci = tid; ci < 512; ci += 256) {      // child-sum
        int m = ci >> 4, j0 = (ci & 15) * 8;
        bf16x8 h0 = *(const bf16x8*)&HC[2 * m][j0];
        bf16x8 h1 = *(const bf16x8*)&HC[2 * m + 1][j0];
        bf16_t s[8];
#pragma unroll
        for (int j = 0; j < 8; j++) s[j] = (bf16_t)((float)h0[j] + (float)h1[j]);
        *(bf16x8*)&HT[m][j0] = *(bf16x8*)&s[0];
    }
    __syncthreads();

    const int wave = tid >> 6, lane = tid & 63;
    const int quad = lane >> 4, lc = lane & 15;

    const bf16_t* UiB = SW + 65536;                // Ui,Uf,Uo,Uu slots
    const bf16_t* UfB = UiB + 32768;
    const bf16_t* UoB = UfB + 32768;
    const bf16_t* UuB = UoB + 32768;

    f32x4 accI[2][2], accO[2][2], accU[2][2], accF[2][4];
#pragma unroll
    for (int nt = 0; nt < 2; nt++) {
#pragma unroll
        for (int mt = 0; mt < 2; mt++) {
            accI[nt][mt] = (f32x4){0.f, 0.f, 0.f, 0.f};
            accO[nt][mt] = (f32x4){0.f, 0.f, 0.f, 0.f};
            accU[nt][mt] = (f32x4){0.f, 0.f, 0.f, 0.f};
        }
#pragma unroll
        for (int mt = 0; mt < 4; mt++) accF[nt][mt] = (f32x4){0.f, 0.f, 0.f, 0.f};
    }

    for (int kb = 0; kb < 4; kb++) {
        const int k0 = kb * 32 + quad * 8;
        bf16x8 at[2], ac[4];
        at[0] = *(const bf16x8*)&HT[lc][k0];
        at[1] = *(const bf16x8*)&HT[16 + lc][k0];
#pragma unroll
        for (int mt = 0; mt < 4; mt++) ac[mt] = *(const bf16x8*)&HC[mt * 16 + lc][k0];
#pragma unroll
        for (int nt = 0; nt < 2; nt++) {
            const int ntg = 2 * wave + nt;
            const size_t boff = ((size_t)(ntg * 4 + kb) * 64 + lane) * 8;
            bf16x8 bIh = *(const bf16x8*)(UiB + boff);
            bf16x8 bIl = *(const bf16x8*)(UiB + 16384 + boff);
            bf16x8 bOh = *(const bf16x8*)(UoB + boff);
            bf16x8 bOl = *(const bf16x8*)(UoB + 16384 + boff);
            bf16x8 bUh = *(const bf16x8*)(UuB + boff);
            bf16x8 bUl = *(const bf16x8*)(UuB + 16384 + boff);
            bf16x8 bFh = *(const bf16x8*)(UfB + boff);
            bf16x8 bFl = *(const bf16x8*)(UfB + 16384 + boff);
#pragma unroll
            for (int mt = 0; mt < 2; mt++) {
                accI[nt][mt] = MFMA16(at[mt], bIh, accI[nt][mt]);
                accI[nt][mt] = MFMA16(at[mt], bIl, accI[nt][mt]);
                accO[nt][mt] = MFMA16(at[mt], bOh, accO[nt][mt]);
                accO[nt][mt] = MFMA16(at[mt], bOl, accO[nt][mt]);
                accU[nt][mt] = MFMA16(at[mt], bUh, accU[nt][mt]);
                accU[nt][mt] = MFMA16(at[mt], bUl, accU[nt][mt]);
            }
#pragma unroll
            for (int mt = 0; mt < 4; mt++) {
                accF[nt][mt] = MFMA16(ac[mt], bFh, accF[nt][mt]);
                accF[nt][mt] = MFMA16(ac[mt], bFl, accF[nt][mt]);
            }
        }
    }

    // --- epilogue phase 1: f-path (in-lane child pair), write S
    const bf16_t* Xf = X + (size_t)Mint * 128;     // f plane
#pragma unroll
    for (int nt = 0; nt < 2; nt++) {
        const int col = (2 * wave + nt) * 16 + lc;
#pragma unroll
        for (int mt = 0; mt < 4; mt++) {
#pragma unroll
            for (int pi = 0; pi < 2; pi++) {
                int pl = mt * 8 + quad * 2 + pi;          // parent local [0,32)
                int pg = n0 + pl;
                float xf = (float)Xf[(size_t)(sl + pg) * 128 + col];
                float f0 = sigm(xf + accF[nt][mt][2 * pi]);
                float f1 = sigm(xf + accF[nt][mt][2 * pi + 1]);
                int ch0 = 2 * pg;                         // child local in child level
                int ch1 = 2 * pg + 1;
                if (ch0 > nch - 1) ch0 = nch - 1;         // clamp (tiny-level safety)
                if (ch1 > nch - 1) ch1 = nch - 1;
                float c0v, c1v;
                if (cLeaf) {
                    c0v = (float)cLeaf[(size_t)ch0 * 128 + col];
                    c1v = (float)cLeaf[(size_t)ch1 * 128 + col];
                } else {
                    c0v = cInt[(size_t)(sl2 + ch0) * 128 + col];
                    c1v = cInt[(size_t)(sl2 + ch1) * 128 + col];
                }
                S[pl][col] = f0 * c0v + f1 * c1v;
            }
        }
    }
    __syncthreads();

    // --- epilogue phase 2: i/o/u path + cell update
    const bf16_t* Xi = X;
    const bf16_t* Xo = X + (size_t)2 * Mint * 128;
    const bf16_t* Xu = X + (size_t)3 * Mint * 128;
#pragma unroll
    for (int nt = 0; nt < 2; nt++) {
        const int col = (2 * wave + nt) * 16 + lc;
#pragma unroll
        for (int mt = 0; mt < 2; mt++) {
#pragma unroll
            for (int r = 0; r < 4; r++) {
                int pl = mt * 16 + quad * 4 + r;
                int pg = n0 + pl;
                if (pg < nl) {
                    size_t xoff = (size_t)(sl + pg) * 128 + col;
                    float iv = sigm((float)Xi[xoff] + accI[nt][mt][r]);
                    float ov = sigm((float)Xo[xoff] + accO[nt][mt][r]);
                    float uv = tanh_((float)Xu[xoff] + accU[nt][mt][r]);
                    float cv = iv * uv + S[pl][col];
                    float hv = ov * tanh_(cv);
                    h[(size_t)(sl + pg) * 128 + col]    = (bf16_t)hv;
                    cInt[(size_t)(sl + pg) * 128 + col] = cv;
                }
            }
        }
    }
}

__global__ __launch_bounds__(256)
void k_out(const bf16_t* __restrict__ h, const float* __restrict__ cInt,
           float* __restrict__ out)
{
    int t = threadIdx.x;
    if (t < 128)      out[t] = (float)h[t];
    else if (t < 256) out[t] = cInt[t - 128];
}

// ---------------------------------------------------------------------------
extern "C" void kernel_launch(void* const* d_in, const int* in_sizes, int n_in,
                              void* d_out, int out_size, void* d_ws, size_t ws_size,
                              hipStream_t stream)
{
    const float* x   = (const float*)d_in[0];
    const float* Wi  = (const float*)d_in[1];
    const float* bi  = (const float*)d_in[2];
    const float* Ui  = (const float*)d_in[3];
    const float* Wf  = (const float*)d_in[4];
    const float* bf_ = (const float*)d_in[5];
    const float* Uf  = (const float*)d_in[6];
    const float* Wo  = (const float*)d_in[7];
    const float* bo  = (const float*)d_in[8];
    const float* Uo  = (const float*)d_in[9];
    const float* Wu  = (const float*)d_in[10];
    const float* bu  = (const float*)d_in[11];
    const float* Uu  = (const float*)d_in[12];

    int Ntot  = in_sizes[0] / 128;                       // 2^(d+1)-1 nodes
    int depth = 31 - __builtin_clz((unsigned)(Ntot + 1)) - 1;
    int NL    = 1 << depth;
    int Mint  = NL - 1;                                  // internal nodes

    // workspace: SW 384KB | X bf16 [4][Mint][128] | h bf16 [Ntot][128]
    //            | cInt fp32 [Mint][128] | cLeaf bf16 [NL][128]   (~288 MiB @ d=17)
    char* w = (char*)d_ws;
    bf16_t* SW    = (bf16_t*)w;                     w += 393216;
    bf16_t* X     = (bf16_t*)w;                     w += (size_t)4 * Mint * 128 * 2;
    bf16_t* h     = (bf16_t*)w;                     w += (size_t)Ntot * 128 * 2;
    float*  cInt  = (float*)w;                      w += (size_t)Mint * 128 * 4;
    bf16_t* cLeaf = (bf16_t*)w;

    k_prep<<<8, 256, 0, stream>>>(Wi, Wf, Wo, Wu, Ui, Uf, Uo, Uu, SW);

    int iB = (Mint + 63) / 64;
    int lB = (NL + 63) / 64;
    k_main<<<iB + lB, 256, 0, stream>>>(x, SW, bi, bf_, bo, bu,
                                        X, h, cLeaf, Mint, Ntot, iB);

    for (int l = depth - 1; l >= 0; --l) {
        int nl = 1 << l, sl = nl - 1;
        int blocks = (nl + 31) / 32;
        const bf16_t* cL = (l == depth - 1) ? cLeaf : nullptr;
        k_level<<<blocks, 256, 0, stream>>>(X, SW, h, cInt, cL, Mint, sl, nl);
    }
    k_out<<<1, 256, 0, stream>>>(h, cInt, (float*)d_out);
}